// Round 7
// baseline (198.313 us; speedup 1.0000x reference)
//
#include <hip/hip_runtime.h>

// Truncated E-step (round 7 == round 6 resubmit; broker timeout last round).
//   z_k = x . w[u_k] + b[u_k]; noise logit == NOISE_LOG_PROP (shift-invariance).
//   stats = P^T X done per 128-spike chunk: dense P[257][128] f16 in LDS
//   (dup-merged in registers, duplicates -> trash row 256), XT[144][128] f16
//   (row 128 = ones -> count column free), mfma_f32_16x16x32_f16, acc in VGPR
//   across chunks, single Q.17 integer-atomic flush (native u32 atomics;
//   f32 LDS atomics are CAS-slow on this toolchain - rounds 1-3).

#define UNITS 256
#define D 128
#define KCAND 10
#define NOISE_LOGIT (-2.0f)
#define SCALE 131072.0f          // 2^17
#define INV_SCALE (1.0f / 131072.0f)
#define GSTATS_ELEMS (UNITS * (D + 1))  // stride 129

#define ROWB 256                 // bytes per LDS tile row (128 f16)
#define PT_ROWS 257              // 256 units + trash row
#define PT_BYTES (PT_ROWS * ROWB)        // 65792
#define XT_BASE PT_BYTES
#define XT_ROWS 144              // dims 0..127, 128=ones, 129..143 zero pad
#define LDS_BYTES (XT_BASE + XT_ROWS * ROWB)  // 102656

typedef _Float16 f16x8 __attribute__((ext_vector_type(8)));
typedef float f32x4 __attribute__((ext_vector_type(4)));

template <int CTRL>
__device__ __forceinline__ float dpp_add(float v) {
  const int p = __builtin_amdgcn_update_dpp(0, __float_as_int(v), CTRL, 0xF, 0xF, true);
  return v + __int_as_float(p);
}

// row-local XOR swizzle: spreads stride-256B column accesses over 8 banks,
// keeps 16B alignment (flips byte-addr bits 4..6 only)
__device__ __forceinline__ int swz(int row, int byteInRow) {
  return byteInRow ^ ((row & 7) << 4);
}

// ---- prep: w[u][j]=mu*iv, b[u]=logprop-0.5*sum(mu^2*iv); zero gstats ----
__global__ void prep_kernel(const float* __restrict__ means,
                            const float* __restrict__ log_noise_var,
                            const float* __restrict__ log_prop,
                            float* __restrict__ w,
                            float* __restrict__ b,
                            unsigned* __restrict__ gstats) {
  const int u = blockIdx.x;
  const int j = threadIdx.x;  // 128
  const float iv = __expf(-log_noise_var[j]);
  const float mu = means[u * D + j];
  const float wv = mu * iv;
  w[u * D + j] = wv;
  float q = mu * wv;
#pragma unroll
  for (int off = 32; off; off >>= 1) q += __shfl_xor(q, off);
  __shared__ float red[2];
  if ((j & 63) == 0) red[j >> 6] = q;
  __syncthreads();
  if (j == 0) b[u] = log_prop[u] - 0.5f * (red[0] + red[1]);
  for (int i = u * D + j; i < GSTATS_ELEMS; i += UNITS * D) gstats[i] = 0u;
}

// ---- fused: resp (VALU dots) + stats (MFMA on dense per-chunk P) ----
__global__ void __launch_bounds__(1024) fused_kernel(
    const float* __restrict__ x, const int* __restrict__ cand,
    const float* __restrict__ wmat, const float* __restrict__ bvec,
    unsigned* __restrict__ gstats, int n) {
  extern __shared__ char smem[];
  const int tid = threadIdx.x;
  const int lane = tid & 63;
  const int wid = tid >> 6;   // 16 waves; wave = one 16-unit M-tile
  const int g = lane >> 3;    // 8 spikes per wave per chunk
  const int l = lane & 7;     // 8 lanes per spike

  // one-time XT init: row 128 = ones (count col), rows 129..143 = 0 (pad)
  if (tid < 64)
    ((unsigned*)(smem + XT_BASE + 128 * ROWB))[tid] = 0x3C003C00u;  // 1.0h x2
  if (tid < 240)
    ((uint4*)(smem + XT_BASE + 129 * ROWB))[tid] = make_uint4(0, 0, 0, 0);

  f32x4 acc[9];
#pragma unroll
  for (int nt = 0; nt < 9; ++nt) acc[nt] = (f32x4){0.f, 0.f, 0.f, 0.f};

  const int spb = n >> 8;        // 512 spikes per block
  const int nchunks = spb >> 7;  // 4 chunks of 128
  const int blockBase = blockIdx.x * spb;

  for (int t = 0; t < nchunks; ++t) {
    __syncthreads();  // prev MFMA done (and one-time init visible)
    // zero P tile (4112 uint4)
    {
      uint4* p = (uint4*)smem;
#pragma unroll
      for (int i = 0; i < 5; ++i) {
        const int idx = tid + i * 1024;
        if (idx < (PT_BYTES >> 4)) p[idx] = make_uint4(0, 0, 0, 0);
      }
    }
    __syncthreads();

    const int chunkBase = blockBase + (t << 7);
    const int spike = chunkBase + (wid << 3) + g;
    const int sl = (wid << 3) + g;  // column in P/XT

    // ---- dot phase (proven 8-lane fragment layout) ----
    const float* xrow = x + (size_t)spike * D;
    float xv[16];
#pragma unroll
    for (int q = 0; q < 4; ++q) {
      const float4 tv = *reinterpret_cast<const float4*>(xrow + q * 32 + l * 4);
      xv[4 * q + 0] = tv.x; xv[4 * q + 1] = tv.y;
      xv[4 * q + 2] = tv.z; xv[4 * q + 3] = tv.w;
    }
    int uc[KCAND];
#pragma unroll
    for (int k = 0; k < KCAND; ++k) uc[k] = cand[(size_t)spike * KCAND + k];

    float e[KCAND];
#pragma unroll
    for (int k = 0; k < KCAND; ++k) {
      const float* wrow = wmat + (size_t)uc[k] * D;
      float a = 0.f;
#pragma unroll
      for (int q = 0; q < 4; ++q) {
        const float4 tv = *reinterpret_cast<const float4*>(wrow + q * 32 + l * 4);
        a = fmaf(xv[4 * q + 0], tv.x, a);
        a = fmaf(xv[4 * q + 1], tv.y, a);
        a = fmaf(xv[4 * q + 2], tv.z, a);
        a = fmaf(xv[4 * q + 3], tv.w, a);
      }
      a = dpp_add<0xB1>(a);   // xor 1
      a = dpp_add<0x4E>(a);   // xor 2
      a += __shfl_xor(a, 4);  // xor 4 -> all 8 lanes hold the dot
      e[k] = a + bvec[uc[k]];
    }

    // ---- softmax over [z..., NOISE_LOGIT] (replicated per 8-lane group) ----
    float m = NOISE_LOGIT;
#pragma unroll
    for (int k = 0; k < KCAND; ++k) m = fmaxf(m, e[k]);
    float ssum = __expf(NOISE_LOGIT - m);
#pragma unroll
    for (int k = 0; k < KCAND; ++k) { e[k] = __expf(e[k] - m); ssum += e[k]; }
    const float rinv = 1.f / ssum;
#pragma unroll
    for (int k = 0; k < KCAND; ++k) e[k] *= rinv;

    // ---- P writes with in-register duplicate merge ----
    // primary: lane l owns slot l; first-occurrence slot writes sum of all
    // equal-unit slots, later duplicates -> trash row 256 (never read).
    {
      int u0 = uc[0];
#pragma unroll
      for (int k = 1; k < 8; ++k) { const bool p = (l == k); u0 = p ? uc[k] : u0; }
      bool first = true; float rsum = 0.f;
#pragma unroll
      for (int j = 0; j < KCAND; ++j) {
        const bool eq = (uc[j] == u0);
        first = first && !(eq && (j < l));
        rsum += (eq && (j >= l)) ? e[j] : 0.f;
      }
      const int urow = first ? u0 : 256;
      *(_Float16*)(smem + urow * ROWB + swz(urow, sl * 2)) = (_Float16)rsum;
      // secondary: lanes 0,1 own slots 8,9
      const int mk = 8 + l;
      const int u1 = (l == 0) ? uc[8] : uc[9];
      bool first2 = true; float rsum2 = 0.f;
#pragma unroll
      for (int j = 0; j < KCAND; ++j) {
        const bool eq = (uc[j] == u1);
        first2 = first2 && !(eq && (j < mk));
        rsum2 += (eq && (j >= mk)) ? e[j] : 0.f;
      }
      const int urow2 = first2 ? u1 : 256;
      if (l < 2)
        *(_Float16*)(smem + urow2 * ROWB + swz(urow2, sl * 2)) = (_Float16)rsum2;
    }

    // ---- XT writes: XT[dim][sl] f16, swizzled (L1-hot x reload) ----
#pragma unroll
    for (int s = 0; s < 8; ++s) {
      const float* xr = x + (size_t)(chunkBase + (wid << 3) + s) * D;
      const int sls = (wid << 3) + s;
      const float xa = xr[lane];
      const float xb = xr[lane + 64];
      *(_Float16*)(smem + XT_BASE + lane * ROWB + swz(lane, sls * 2)) = (_Float16)xa;
      const int d2 = lane + 64;
      *(_Float16*)(smem + XT_BASE + d2 * ROWB + swz(d2, sls * 2)) = (_Float16)xb;
    }
    __syncthreads();

    // ---- MFMA: acc[nt] += PT[m-tile] x XT (K=128, 4 ksteps) ----
    const int mm = lane & 15;
    const int kq = lane >> 4;  // 0..3
#pragma unroll
    for (int ks = 0; ks < 4; ++ks) {
      const int kbyte = ks * 64 + kq * 16;  // (ks*32 + kq*8) f16 elems
      const int arow = (wid << 4) + mm;
      const f16x8 a = *(const f16x8*)(smem + arow * ROWB + swz(arow, kbyte));
#pragma unroll
      for (int nt = 0; nt < 9; ++nt) {
        const int nrow = (nt << 4) + mm;
        const f16x8 bfr = *(const f16x8*)(smem + XT_BASE + nrow * ROWB + swz(nrow, kbyte));
        acc[nt] = __builtin_amdgcn_mfma_f32_16x16x32_f16(a, bfr, acc[nt], 0, 0, 0);
      }
    }
  }

  // ---- epilogue: C[unit][dim]; unit=(lane>>4)*4+reg (+16*wid), dim=nt*16+(lane&15)
#pragma unroll
  for (int nt = 0; nt < 9; ++nt) {
#pragma unroll
    for (int r = 0; r < 4; ++r) {
      const int unit = (wid << 4) + ((lane >> 4) << 2) + r;
      const int dim = (nt << 4) + (lane & 15);
      if (dim <= D) {  // nt<8 always; nt==8 -> count col only (lane&15)==0
        const int q = __float2int_rn(acc[nt][r] * SCALE);
        atomicAdd(&gstats[unit * (D + 1) + dim], (unsigned)q);
      }
    }
  }
}

// ---- finish: Q.17 integer -> f32 output ----
__global__ void finish_kernel(const unsigned* __restrict__ gstats,
                              float* __restrict__ out) {
  const int i = blockIdx.x * 256 + threadIdx.x;
  if (i < GSTATS_ELEMS) out[i] = (float)(int)gstats[i] * INV_SCALE;
}

extern "C" void kernel_launch(void* const* d_in, const int* in_sizes, int n_in,
                              void* d_out, int out_size, void* d_ws, size_t ws_size,
                              hipStream_t stream) {
  const float* features = (const float*)d_in[0];
  const float* means    = (const float*)d_in[1];
  const float* lnv      = (const float*)d_in[2];
  const float* lprop    = (const float*)d_in[3];
  const int*   cand     = (const int*)d_in[4];
  float* out = (float*)d_out;

  // ws: w[256*128] f32 | b[256] f32 | gstats[33024] u32
  float* w = (float*)d_ws;
  float* b = w + UNITS * D;
  unsigned* gstats = (unsigned*)(b + UNITS);

  const int n = in_sizes[0] / D;  // 131072

  prep_kernel<<<UNITS, D, 0, stream>>>(means, lnv, lprop, w, b, gstats);

  hipFuncSetAttribute((const void*)fused_kernel,
                      hipFuncAttributeMaxDynamicSharedMemorySize, LDS_BYTES);
  fused_kernel<<<n / 512, 1024, LDS_BYTES, stream>>>(features, cand, w, b, gstats, n);

  finish_kernel<<<(GSTATS_ELEMS + 255) / 256, 256, 0, stream>>>(gstats, out);
}

// Round 8
// 173.486 us; speedup vs baseline: 1.1431x; 1.1431x over previous
//
#include <hip/hip_runtime.h>

// Truncated E-step (round 8): round-5 structure + u64-packed Q.17 scatter.
//   z_k = x . w[u_k] + b[u_k]; noise logit == NOISE_LOG_PROP (shift-invariance).
//   Scatter: ONE ds_add_u64 per (spike,cand) covering 128 dims:
//     low32  = int(r*x[j]   *2^17) + 2^22   (bias -> non-negative, no carry-out)
//     high32 = int(r*x[j+64]*2^17) + 2^22
//   Tail cell per unit row: low = count-col Q.17, high = contribution count C.
//   Flush subtracts C*2^22 per word (exact, modular). f32->int via the
//   1.5*2^23 magic-number fma (RNE, |v| < 2^22 guaranteed: |x|<~6, r<=1).
//   LDS f32 atomics are CAS-slow on this toolchain (rounds 1-3); integer
//   ds_add_u32/u64 are native (round 3: 888 -> 72us).

#define UNITS 256
#define D 128
#define KCAND 10
#define NOISE_LOGIT (-2.0f)
#define ROWU64 65                      // 64 dim-cells + 1 tail per unit row
#define LDS_U64 (UNITS * ROWU64)       // 16640 u64 = 133120 B
#define SCALE 131072.0f                // 2^17
#define INV_SCALE (1.0f / 131072.0f)
#define MAGIC 12582912.0f              // 1.5 * 2^23
#define GSTATS_ELEMS (UNITS * (D + 1))

template <int CTRL>
__device__ __forceinline__ float dpp_add(float v) {
  // quad_perm lane-xor add: 0xB1 -> xor1, 0x4E -> xor2
  const int p = __builtin_amdgcn_update_dpp(0, __float_as_int(v), CTRL, 0xF, 0xF, true);
  return v + __int_as_float(p);
}

// ---- prep: w[u][j]=mu*iv, b[u]=logprop-0.5*sum(mu^2*iv); zero gstats ----
__global__ void prep_kernel(const float* __restrict__ means,
                            const float* __restrict__ log_noise_var,
                            const float* __restrict__ log_prop,
                            float* __restrict__ w,
                            float* __restrict__ b,
                            unsigned* __restrict__ gstats) {
  const int u = blockIdx.x;
  const int j = threadIdx.x;  // 128
  const float iv = __expf(-log_noise_var[j]);
  const float mu = means[u * D + j];
  const float wv = mu * iv;
  w[u * D + j] = wv;
  float q = mu * wv;
#pragma unroll
  for (int off = 32; off; off >>= 1) q += __shfl_xor(q, off);
  __shared__ float red[2];
  if ((j & 63) == 0) red[j >> 6] = q;
  __syncthreads();
  if (j == 0) b[u] = log_prop[u] - 0.5f * (red[0] + red[1]);
  for (int i = u * D + j; i < GSTATS_ELEMS; i += UNITS * D) gstats[i] = 0u;
}

// ---- fused: dots + softmax + u64-packed Q.17 LDS scatter + flush ----
__global__ void __launch_bounds__(1024, 1) fused_kernel(
    const float* __restrict__ x, const int* __restrict__ cand,
    const float* __restrict__ wmat, const float* __restrict__ bvec,
    unsigned* __restrict__ gstats, int n) {
  extern __shared__ unsigned long long tile[];  // [UNITS][ROWU64]
  const int tid = threadIdx.x;
  {
    uint4* p = (uint4*)tile;  // 133120 B = 8320 uint4
    for (int i = tid; i < (LDS_U64 >> 1); i += 1024) p[i] = make_uint4(0, 0, 0, 0);
  }
  __syncthreads();

  const int lane = tid & 63;
  const int wid = tid >> 6;   // 16 waves
  const int g = lane >> 3;    // spike slot (8 spikes per wave-iter)
  const int l = lane & 7;     // 8 lanes per spike, 16 dims each

  const int spb = n >> 8;     // 512 spikes per block
  const int wsp = spb >> 4;   // 32 per wave
  const int base = blockIdx.x * spb + wid * wsp;

  for (int it = 0; it < (wsp >> 3); ++it) {  // 4 iters of 8 spikes
    const int spike8 = base + it * 8;
    const int spike = spike8 + g;

    // ---- dot phase: x fragment, dims q*32 + l*4 + i ----
    const float* xrow = x + (size_t)spike * D;
    float xv[16];
#pragma unroll
    for (int q = 0; q < 4; ++q) {
      const float4 t = *reinterpret_cast<const float4*>(xrow + q * 32 + l * 4);
      xv[4 * q + 0] = t.x; xv[4 * q + 1] = t.y;
      xv[4 * q + 2] = t.z; xv[4 * q + 3] = t.w;
    }

    int uc[KCAND];
#pragma unroll
    for (int k = 0; k < KCAND; ++k) uc[k] = cand[(size_t)spike * KCAND + k];

    float e[KCAND];
#pragma unroll
    for (int k = 0; k < KCAND; ++k) {
      const float* wrow = wmat + (size_t)uc[k] * D;
      float acc = 0.f;
#pragma unroll
      for (int q = 0; q < 4; ++q) {
        const float4 t = *reinterpret_cast<const float4*>(wrow + q * 32 + l * 4);
        acc = fmaf(xv[4 * q + 0], t.x, acc);
        acc = fmaf(xv[4 * q + 1], t.y, acc);
        acc = fmaf(xv[4 * q + 2], t.z, acc);
        acc = fmaf(xv[4 * q + 3], t.w, acc);
      }
      acc = dpp_add<0xB1>(acc);   // xor 1
      acc = dpp_add<0x4E>(acc);   // xor 2
      acc += __shfl_xor(acc, 4);  // xor 4
      e[k] = acc + bvec[uc[k]];
    }

    // ---- softmax over [z_0..z_9, NOISE_LOGIT] (replicated in 8 lanes) ----
    float m = NOISE_LOGIT;
#pragma unroll
    for (int k = 0; k < KCAND; ++k) m = fmaxf(m, e[k]);
    float ssum = __expf(NOISE_LOGIT - m);
#pragma unroll
    for (int k = 0; k < KCAND; ++k) { e[k] = __expf(e[k] - m); ssum += e[k]; }
    const float rinv = 1.f / ssum;
#pragma unroll
    for (int k = 0; k < KCAND; ++k) e[k] *= rinv;

    // ---- tail adds: count-col (Q.17, low) + contribution count (+1, high)
    // lane l owns pair (spike g, cand l); lanes 0,1 also pairs (g, 8/9).
    {
      float rsel = e[0]; int usel = uc[0];
#pragma unroll
      for (int k = 1; k < 8; ++k) {
        const bool p = (l == k);
        rsel = p ? e[k] : rsel;
        usel = p ? uc[k] : usel;
      }
      const unsigned lo = __float_as_uint(fmaf(rsel, SCALE, MAGIC)) - 0x4B400000u;
      atomicAdd(&tile[usel * ROWU64 + 64], (1ull << 32) | (unsigned long long)lo);
      const float rs2 = (l == 0) ? e[8] : e[9];
      const int us2 = (l == 0) ? uc[8] : uc[9];
      if (l < 2) {
        const unsigned lo2 = __float_as_uint(fmaf(rs2, SCALE, MAGIC)) - 0x4B400000u;
        atomicAdd(&tile[us2 * ROWU64 + 64], (1ull << 32) | (unsigned long long)lo2);
      }
    }

    // ---- x in wave layout, pre-scaled by 2^17 (L1-hot reload) ----
    float xsa[8], xsb[8];
#pragma unroll
    for (int s = 0; s < 8; ++s) {
      const float* xr = x + (size_t)(spike8 + s) * D;
      xsa[s] = xr[lane] * SCALE;
      xsb[s] = xr[lane + 64] * SCALE;
    }

    // ---- scatter: ONE ds_add_u64 per (spike,cand) covering 128 dims.
    // lane j: low = dim j (biased +2^22), high = dim j+64 (biased +2^22).
    // bits(fma(r,xs,MAGIC)) - 0x4B400000 + 0x00400000 = bits + 0xB5000000.
#pragma unroll
    for (int s = 0; s < 8; ++s) {
#pragma unroll
      for (int k = 0; k < KCAND; ++k) {
        const int u = __builtin_amdgcn_readlane(uc[k], s * 8);
        const float r = __int_as_float(
            __builtin_amdgcn_readlane(__float_as_int(e[k]), s * 8));
        const unsigned lo = __float_as_uint(fmaf(r, xsa[s], MAGIC)) + 0xB5000000u;
        const unsigned hi = __float_as_uint(fmaf(r, xsb[s], MAGIC)) + 0xB5000000u;
        atomicAdd(&tile[(unsigned)u * ROWU64 + lane],
                  ((unsigned long long)hi << 32) | (unsigned long long)lo);
      }
    }
  }

  __syncthreads();
  // ---- flush: per row, correct bias (C*2^22 per word) and atomically add
  for (int rr = 0; rr < 16; ++rr) {
    const int u = wid * 16 + rr;
    const unsigned long long cell = tile[u * ROWU64 + lane];
    const unsigned long long tail = tile[u * ROWU64 + 64];  // broadcast read
    const unsigned corr = (unsigned)(tail >> 32) << 22;     // C * 2^22
    atomicAdd(&gstats[u * (D + 1) + lane], (unsigned)cell - corr);
    atomicAdd(&gstats[u * (D + 1) + 64 + lane], (unsigned)(cell >> 32) - corr);
    if (lane == 0) atomicAdd(&gstats[u * (D + 1) + D], (unsigned)tail);
  }
}

// ---- finish: Q.17 integer -> f32 output ----
__global__ void finish_kernel(const unsigned* __restrict__ gstats,
                              float* __restrict__ out) {
  const int i = blockIdx.x * 256 + threadIdx.x;
  if (i < GSTATS_ELEMS) out[i] = (float)(int)gstats[i] * INV_SCALE;
}

extern "C" void kernel_launch(void* const* d_in, const int* in_sizes, int n_in,
                              void* d_out, int out_size, void* d_ws, size_t ws_size,
                              hipStream_t stream) {
  const float* features = (const float*)d_in[0];
  const float* means    = (const float*)d_in[1];
  const float* lnv      = (const float*)d_in[2];
  const float* lprop    = (const float*)d_in[3];
  const int*   cand     = (const int*)d_in[4];
  float* out = (float*)d_out;

  // ws: w[256*128] f32 | b[256] f32 | gstats[33024] u32
  float* w = (float*)d_ws;
  float* b = w + UNITS * D;
  unsigned* gstats = (unsigned*)(b + UNITS);

  const int n = in_sizes[0] / D;  // 131072

  prep_kernel<<<UNITS, D, 0, stream>>>(means, lnv, lprop, w, b, gstats);

  const int lds_bytes = LDS_U64 * 8;  // 133120
  hipFuncSetAttribute((const void*)fused_kernel,
                      hipFuncAttributeMaxDynamicSharedMemorySize, lds_bytes);
  fused_kernel<<<256, 1024, lds_bytes, stream>>>(features, cand, w, b, gstats, n);

  finish_kernel<<<(GSTATS_ELEMS + 255) / 256, 256, 0, stream>>>(gstats, out);
}